// Round 3
// baseline (1171.513 us; speedup 1.0000x reference)
//
#include <hip/hip_runtime.h>
#include <hip/hip_bf16.h>
#include <stdint.h>

// Problem constants
#define B_   4
#define C_   256
#define H_   200
#define W_   336
#define OC_  512
#define HP_  202           // H + 2 (pad)
#define WP_  338           // W + 2 (pad)
#define M_   (B_*H_*W_)    // 268800 pixels = 2100 * 128 exactly
#define MTILES (M_/128)    // 2100
#define OUT0_ (M_*18)      // 4,838,400 cls elements
#define OUT_TOTAL_ (M_*54) // 14,515,200

// Workspace layout (bytes)
#define XP_ELEMS  ((size_t)B_*HP_*WP_*C_)   // 69,914,624
#define XP_BYTES  (XP_ELEMS*2)              // ~139.8 MB
#define W1T_ELEMS ((size_t)9*OC_*C_)        // 1,179,648
#define W1T_OFF   XP_BYTES
#define WHB_OFF   (W1T_OFF + W1T_ELEMS*2)

typedef unsigned short ushortT;
typedef __attribute__((ext_vector_type(8))) short bf16x8;   // 8 bf16 = 4 VGPR
typedef __attribute__((ext_vector_type(4))) float f32x4;

static __device__ __forceinline__ ushortT f2bf(float x) {
    union { float f; uint32_t u; } v; v.f = x;
    uint32_t r = v.u + 0x7fff + ((v.u >> 16) & 1);   // RNE
    return (ushortT)(r >> 16);
}

// ---------------------------------------------------------------------------
// Pre-pass 0: zero only the halo of the padded buffer.
__global__ __launch_bounds__(256) void zero_halo(ushortT* __restrict__ Xp) {
    int i = blockIdx.x * 256 + threadIdx.x;
    if (i >= 4 * 1076 * 32) return;
    int pix = i >> 5, ch = (i & 31) * 8;
    int b = pix / 1076, r = pix % 1076;
    int h, w;
    if (r < 338)      { h = 0;   w = r; }
    else if (r < 676) { h = 201; w = r - 338; }
    else { r -= 676; h = 1 + (r >> 1); w = (r & 1) ? 337 : 0; }
    size_t dst = (((size_t)b*HP_ + h)*WP_ + w)*C_ + ch;
    *(uint4*)(Xp + dst) = make_uint4(0, 0, 0, 0);
}

// Pre-pass 1: NCHW fp32 -> padded NHWC bf16 via LDS tile transpose.
__global__ __launch_bounds__(256) void pad_transpose(const float* __restrict__ X,
                                                     ushortT* __restrict__ Xp) {
    int bid = blockIdx.x;
    int wc = bid % 6; int bh = bid / 6;
    int h = bh % H_;  int b = bh / H_;
    int w0 = wc * 64;
    int t = threadIdx.x;
    __shared__ ushortT tile[64 * 65];

    for (int c0 = 0; c0 < C_; c0 += 64) {
        if (c0) __syncthreads();
        int col  = t & 63;
        int rowb = t >> 6;
        #pragma unroll
        for (int rr = 0; rr < 16; ++rr) {
            int row = rowb * 16 + rr;
            int w = w0 + col;
            float val = 0.f;
            if (w < W_)
                val = X[(((size_t)(b*C_ + c0 + row))*H_ + h)*W_ + w];
            tile[row*65 + col] = f2bf(val);
        }
        __syncthreads();
        int pixel = t >> 2;
        int csub  = (t & 3) * 16;
        int w = w0 + pixel;
        if (w < W_) {
            union { ushortT u[16]; uint4 q[2]; } vals;
            #pragma unroll
            for (int j = 0; j < 16; ++j)
                vals.u[j] = tile[(csub + j)*65 + pixel];
            size_t dst = (((size_t)b*HP_ + (h+1))*WP_ + (w+1))*C_ + c0 + csub;
            *(uint4*)(Xp + dst)     = vals.q[0];
            *(uint4*)(Xp + dst + 8) = vals.q[1];
        }
    }
}

// Pre-pass 2: W1 [oc][c][3][3] fp32 -> W1t [rs][oc][c] bf16
__global__ __launch_bounds__(256) void prep_w1(const float* __restrict__ W1,
                                               ushortT* __restrict__ W1t) {
    int t = blockIdx.x * 256 + threadIdx.x;
    if (t >= OC_*C_) return;
    const float* src = W1 + (size_t)t * 9;
    #pragma unroll
    for (int rs = 0; rs < 9; ++rs)
        W1t[(size_t)rs*OC_*C_ + t] = f2bf(src[rs]);
}

// Pre-pass 3: Wc[18][512], Wb[36][512] -> Whb[64][512] bf16 (rows 54..63 zero)
__global__ __launch_bounds__(256) void prep_whb(const float* __restrict__ Wc,
                                                const float* __restrict__ Wb,
                                                ushortT* __restrict__ Whb) {
    int t = blockIdx.x * 256 + threadIdx.x;
    if (t >= 64*512) return;
    int o = t >> 9, oc = t & 511;
    float v = 0.f;
    if (o < 18) v = Wc[o*512 + oc];
    else if (o < 54) v = Wb[(o-18)*512 + oc];
    Whb[t] = f2bf(v);
}

// ---------------------------------------------------------------------------
// Main fused kernel, v3b: BM=128 x BN=512 with the m201-style 8-phase schedule.
// 512 threads / 8 waves (2M x 4N), wave tile 64x128, acc[4][8].
// LDS 160 KB (ushort offsets): Abuf0 [0,8192) Abuf1 [8192,16384)
//                              Bbuf0 [16384,49152) Bbuf1 [49152,81920)
// Per K-tile (BK=64): 4 phases, phase q = (kk=q>>1, nhalf=q&1):
//   [8 ds_read_b128 | staging chunk of tile t+1 ({3,3,2,2} loads)]
//   s_barrier ; lgkmcnt(0)+sched_barrier ; setprio(1) ; 16 MFMA ; setprio(0)
//   ; s_barrier
// vmcnt(3) once per tile, at phase 0 AFTER issuing the next tile's chunk0:
// waits tile t's 10 loads (issued one full tile earlier) while keeping 3 in
// flight. Never drains vmcnt in the main loop (vmcnt(0) only at tile 35).
// Rule #18 hardening: sched_barrier(0) after every inline-asm s_waitcnt so
// the scheduler cannot hoist register-only MFMA past the wait.
// Head GEMM complete per block (K=512) -> direct stores, no atomics.
#define CONV_GRID 2100

#define GLD(gsrc, ldst) __builtin_amdgcn_global_load_lds( \
    (const __attribute__((address_space(1))) uint32_t*)(gsrc), \
    (__attribute__((address_space(3))) uint32_t*)(ldst), 16, 0, 0)

__global__ __launch_bounds__(512, 2) void conv_rpn(
    const ushortT* __restrict__ Xp, const ushortT* __restrict__ W1t,
    const float* __restrict__ b1,  const ushortT* __restrict__ Whb,
    const float* __restrict__ bc,  const float* __restrict__ bb,
    float* __restrict__ out)
{
    extern __shared__ ushortT smem[];

    const int tid  = threadIdx.x;
    const int wave = tid >> 6;          // 0..7
    const int lane = tid & 63;
    const int col  = lane & 15;
    const int quad = lane >> 4;
    const int c7   = col & 7;           // read de-swizzle key (row&7 == col&7)
    const int wm   = (wave >> 2) * 64;  // M offset of this wave (0 or 64)
    const int wn   = (wave & 3) * 128;  // N offset of this wave (0..384)

    // Bijective XCD swizzle for 2100 blocks over 8 XCDs (m204 variant).
    const int bid = blockIdx.x;
    const int xcd = bid & 7, ib = bid >> 3;
    const int mtile = (xcd < 4) ? (xcd*263 + ib) : (1052 + (xcd-4)*262 + ib);

    // Staging: lane (r8 = lane>>3) covers row r8 of each 8-row group; chunk
    // position lane&7 holds logical chunk (lane&7)^r8 (row-XOR swizzle).
    const int r8     = lane >> 3;
    const int lchunk = ((lane & 7) ^ r8) * 8;

    // A source addresses: 2 loads/wave/tile, rows wave*16 + i*8 + r8.
    size_t pixA[2];
    #pragma unroll
    for (int i = 0; i < 2; ++i) {
        int m = mtile*128 + wave*16 + i*8 + r8;
        int b = m / (H_*W_);
        int rem = m % (H_*W_);
        int hh = rem / W_;
        int ww = rem % W_;
        pixA[i] = (((size_t)b*HP_ + hh)*WP_ + ww)*C_ + lchunk;
    }
    // B source: 8 loads/wave/tile, oc rows wave*64 + i*8 + r8.
    const size_t bbase = ((size_t)(wave*64 + r8))*C_ + lchunk;

    f32x4 acc[4][8] = {};

    // Staging chunk q of a K-tile into buffer `buf`.
    // aoff = roff(rs) + cs ; woff = rs*OC_*C_ + bbase + cs.
    auto STAGE_CHUNK = [&](int q, int buf, size_t aoff, size_t woff) {
        ushortT* Ab = smem + buf*8192  + (wave*16)*64;
        ushortT* Bb = smem + 16384 + buf*32768 + (wave*64)*64;
        switch (q) {
        case 0:
            GLD(Xp + pixA[0] + aoff, Ab);
            GLD(Xp + pixA[1] + aoff, Ab + 8*64);
            GLD(W1t + woff,          Bb);
            break;
        case 1:
            GLD(W1t + woff + (size_t)1*8*C_, Bb + 1*8*64);
            GLD(W1t + woff + (size_t)2*8*C_, Bb + 2*8*64);
            GLD(W1t + woff + (size_t)3*8*C_, Bb + 3*8*64);
            break;
        case 2:
            GLD(W1t + woff + (size_t)4*8*C_, Bb + 4*8*64);
            GLD(W1t + woff + (size_t)5*8*C_, Bb + 5*8*64);
            break;
        default:
            GLD(W1t + woff + (size_t)6*8*C_, Bb + 6*8*64);
            GLD(W1t + woff + (size_t)7*8*C_, Bb + 7*8*64);
        }
    };

    // Prologue: stage tile 0 (rs=0, cs=0 -> aoff=0) into buf0.
    STAGE_CHUNK(0, 0, 0, bbase);
    STAGE_CHUNK(1, 0, 0, bbase);
    STAGE_CHUNK(2, 0, 0, bbase);
    STAGE_CHUNK(3, 0, 0, bbase);

    #pragma unroll 1
    for (int t = 0; t < 36; ++t) {
        const int cur = t & 1;
        const ushortT* Al = smem + cur*8192;
        const ushortT* Bl = smem + 16384 + cur*32768;
        const bool pf = (t < 35);
        size_t aoffn = 0, woffn = 0;
        if (pf) {
            int tn = t + 1;
            int rsn = tn >> 2, csn = (tn & 3) << 6;
            aoffn = (size_t)((rsn/3)*WP_ + (rsn%3))*C_ + csn;
            woffn = (size_t)rsn*OC_*C_ + bbase + csn;
        }

        #pragma unroll
        for (int q = 0; q < 4; ++q) {
            const int kk = q >> 1, nh = q & 1;
            const int pc = ((kk*4 + quad) ^ c7) * 8;
            bf16x8 af[4], bfr[4];
            if (q == 0) {
                // Issue next tile's first chunk, then the once-per-tile wait:
                // all of tile t's 10 loads landed; chunk0's 3 stay in flight.
                if (pf) {
                    STAGE_CHUNK(0, cur ^ 1, aoffn, woffn);
                    asm volatile("s_waitcnt vmcnt(3)" ::: "memory");
                } else {
                    asm volatile("s_waitcnt vmcnt(0)" ::: "memory");
                }
                __builtin_amdgcn_sched_barrier(0);
                __builtin_amdgcn_s_barrier();
                __builtin_amdgcn_sched_barrier(0);
                // RAW: reads of freshly-landed tile t go after the barrier.
                #pragma unroll
                for (int mt = 0; mt < 4; ++mt)
                    af[mt] = *(const bf16x8*)&Al[(wm + mt*16 + col)*64 + pc];
                #pragma unroll
                for (int nt = 0; nt < 4; ++nt)
                    bfr[nt] = *(const bf16x8*)&Bl[(wn + nh*64 + nt*16 + col)*64 + pc];
            } else {
                #pragma unroll
                for (int mt = 0; mt < 4; ++mt)
                    af[mt] = *(const bf16x8*)&Al[(wm + mt*16 + col)*64 + pc];
                #pragma unroll
                for (int nt = 0; nt < 4; ++nt)
                    bfr[nt] = *(const bf16x8*)&Bl[(wn + nh*64 + nt*16 + col)*64 + pc];
                if (pf) STAGE_CHUNK(q, cur ^ 1, aoffn, woffn);
                __builtin_amdgcn_s_barrier();
            }
            asm volatile("s_waitcnt lgkmcnt(0)" ::: "memory");
            __builtin_amdgcn_sched_barrier(0);
            __builtin_amdgcn_s_setprio(1);
            #pragma unroll
            for (int mt = 0; mt < 4; ++mt)
                #pragma unroll
                for (int nt = 0; nt < 4; ++nt)
                    acc[mt][nh*4 + nt] = __builtin_amdgcn_mfma_f32_16x16x32_bf16(
                        af[mt], bfr[nt], acc[mt][nh*4 + nt], 0, 0, 0);
            __builtin_amdgcn_s_setprio(0);
            __builtin_amdgcn_sched_barrier(0);
            __builtin_amdgcn_s_barrier();
        }
    }

    // ---- Epilogue: +b1, ReLU, feat -> Fsm[128][512] bf16 (reuses all LDS).
    // Swizzle: 16B-chunk (colc>>3) XOR (row&7), same involution on read.
    // Safe: the loop's final barrier orders all waves' tile-35 ds_reads
    // before any Fsm write.
    ushortT* Fsm = smem;
    float b1v[8];
    #pragma unroll
    for (int nt = 0; nt < 8; ++nt) b1v[nt] = b1[wn + nt*16 + col];
    #pragma unroll
    for (int mt = 0; mt < 4; ++mt)
        #pragma unroll
        for (int nt = 0; nt < 8; ++nt) {
            const float bv = b1v[nt];
            #pragma unroll
            for (int rg = 0; rg < 4; ++rg) {
                int row  = wm + mt*16 + quad*4 + rg;
                int colc = wn + nt*16 + col;
                float v = fmaxf(acc[mt][nt][rg] + bv, 0.f);
                int pos = (((colc >> 3) ^ (row & 7)) << 3) | (colc & 7);
                Fsm[row*512 + pos] = f2bf(v);
            }
        }
    __syncthreads();

    // ---- Head GEMM: M=128 pixels, N=64 (54 used), K=512 (complete).
    f32x4 hacc[4] = {};
    const int hrow = wave*16 + col;
    const int h7   = col & 7;     // hrow&7 == col&7
    const ushortT* Fr = Fsm + hrow*512;
    #pragma unroll
    for (int ks = 0; ks < 16; ++ks) {
        bf16x8 ah = *(const bf16x8*)&Fr[((ks*4 + quad) ^ h7) << 3];
        #pragma unroll
        for (int nt = 0; nt < 4; ++nt) {
            bf16x8 bh = *(const bf16x8*)&Whb[(nt*16 + col)*512 + ks*32 + quad*8];
            hacc[nt] = __builtin_amdgcn_mfma_f32_16x16x32_bf16(
                ah, bh, hacc[nt], 0, 0, 0);
        }
    }

    // ---- Direct stores with head bias (single writer per element).
    #pragma unroll
    for (int nt = 0; nt < 4; ++nt) {
        int o = nt*16 + col;
        float bias = (o < 18) ? bc[o] : (o < 54 ? bb[o - 18] : 0.f);
        #pragma unroll
        for (int rg = 0; rg < 4; ++rg) {
            size_t p = (size_t)mtile*128 + wave*16 + quad*4 + rg;
            float v = hacc[nt][rg] + bias;
            if (o < 18)      out[p*18 + o] = v;
            else if (o < 54) out[OUT0_ + p*36 + (o - 18)] = v;
        }
    }
}

// ---------------------------------------------------------------------------
extern "C" void kernel_launch(void* const* d_in, const int* in_sizes, int n_in,
                              void* d_out, int out_size, void* d_ws, size_t ws_size,
                              hipStream_t stream) {
    const float* X  = (const float*)d_in[0];
    const float* W1 = (const float*)d_in[1];
    const float* b1 = (const float*)d_in[2];
    const float* Wc = (const float*)d_in[3];
    const float* bc = (const float*)d_in[4];
    const float* Wb = (const float*)d_in[5];
    const float* bb = (const float*)d_in[6];
    float* out = (float*)d_out;

    ushortT* Xp  = (ushortT*)d_ws;
    ushortT* W1t = (ushortT*)((char*)d_ws + W1T_OFF);
    ushortT* Whb = (ushortT*)((char*)d_ws + WHB_OFF);

    static bool attr_set = false;
    if (!attr_set) {
        hipFuncSetAttribute((const void*)conv_rpn,
                            hipFuncAttributeMaxDynamicSharedMemorySize, 163840);
        attr_set = true;
    }

    zero_halo<<<(4*1076*32 + 255)/256, 256, 0, stream>>>(Xp);
    pad_transpose<<<B_*H_*6, 256, 0, stream>>>(X, Xp);
    prep_w1<<<(OC_*C_ + 255)/256, 256, 0, stream>>>(W1, W1t);
    prep_whb<<<(64*512 + 255)/256, 256, 0, stream>>>(Wc, Wb, Whb);
    conv_rpn<<<CONV_GRID, 512, 163840, stream>>>(Xp, W1t, b1, Whb, bc, bb, out);
}

// Round 4
// 1167.853 us; speedup vs baseline: 1.0031x; 1.0031x over previous
//
#include <hip/hip_runtime.h>
#include <hip/hip_bf16.h>
#include <stdint.h>

// Problem constants
#define B_   4
#define C_   256
#define H_   200
#define W_   336
#define OC_  512
#define HP_  202           // H + 2 (pad)
#define WP_  338           // W + 2 (pad)
#define M_   (B_*H_*W_)    // 268800 pixels = 1050 * 256 exactly
#define MT256 (M_/256)     // 1050
#define OUT0_ (M_*18)      // 4,838,400 cls elements
#define OUT_TOTAL_ (M_*54) // 14,515,200

// Workspace layout (bytes)
#define XP_ELEMS  ((size_t)B_*HP_*WP_*C_)   // 69,914,624
#define XP_BYTES  (XP_ELEMS*2)              // ~139.8 MB
#define W1T_ELEMS ((size_t)9*OC_*C_)        // 1,179,648
#define W1T_OFF   XP_BYTES
#define WHB_OFF   (W1T_OFF + W1T_ELEMS*2)

typedef unsigned short ushortT;
typedef __attribute__((ext_vector_type(8))) short bf16x8;   // 8 bf16 = 4 VGPR
typedef __attribute__((ext_vector_type(4))) float f32x4;

static __device__ __forceinline__ ushortT f2bf(float x) {
    union { float f; uint32_t u; } v; v.f = x;
    uint32_t r = v.u + 0x7fff + ((v.u >> 16) & 1);   // RNE
    return (ushortT)(r >> 16);
}

// ---------------------------------------------------------------------------
// Pre-pass 0: zero only the halo of the padded buffer.
__global__ __launch_bounds__(256) void zero_halo(ushortT* __restrict__ Xp) {
    int i = blockIdx.x * 256 + threadIdx.x;
    if (i >= 4 * 1076 * 32) return;
    int pix = i >> 5, ch = (i & 31) * 8;
    int b = pix / 1076, r = pix % 1076;
    int h, w;
    if (r < 338)      { h = 0;   w = r; }
    else if (r < 676) { h = 201; w = r - 338; }
    else { r -= 676; h = 1 + (r >> 1); w = (r & 1) ? 337 : 0; }
    size_t dst = (((size_t)b*HP_ + h)*WP_ + w)*C_ + ch;
    *(uint4*)(Xp + dst) = make_uint4(0, 0, 0, 0);
}

// Pre-pass 1: NCHW fp32 -> padded NHWC bf16 via LDS tile transpose.
__global__ __launch_bounds__(256) void pad_transpose(const float* __restrict__ X,
                                                     ushortT* __restrict__ Xp) {
    int bid = blockIdx.x;
    int wc = bid % 6; int bh = bid / 6;
    int h = bh % H_;  int b = bh / H_;
    int w0 = wc * 64;
    int t = threadIdx.x;
    __shared__ ushortT tile[64 * 65];

    for (int c0 = 0; c0 < C_; c0 += 64) {
        if (c0) __syncthreads();
        int col  = t & 63;
        int rowb = t >> 6;
        #pragma unroll
        for (int rr = 0; rr < 16; ++rr) {
            int row = rowb * 16 + rr;
            int w = w0 + col;
            float val = 0.f;
            if (w < W_)
                val = X[(((size_t)(b*C_ + c0 + row))*H_ + h)*W_ + w];
            tile[row*65 + col] = f2bf(val);
        }
        __syncthreads();
        int pixel = t >> 2;
        int csub  = (t & 3) * 16;
        int w = w0 + pixel;
        if (w < W_) {
            union { ushortT u[16]; uint4 q[2]; } vals;
            #pragma unroll
            for (int j = 0; j < 16; ++j)
                vals.u[j] = tile[(csub + j)*65 + pixel];
            size_t dst = (((size_t)b*HP_ + (h+1))*WP_ + (w+1))*C_ + c0 + csub;
            *(uint4*)(Xp + dst)     = vals.q[0];
            *(uint4*)(Xp + dst + 8) = vals.q[1];
        }
    }
}

// Pre-pass 2: W1 [oc][c][3][3] fp32 -> W1t [rs][oc][c] bf16
__global__ __launch_bounds__(256) void prep_w1(const float* __restrict__ W1,
                                               ushortT* __restrict__ W1t) {
    int t = blockIdx.x * 256 + threadIdx.x;
    if (t >= OC_*C_) return;
    const float* src = W1 + (size_t)t * 9;
    #pragma unroll
    for (int rs = 0; rs < 9; ++rs)
        W1t[(size_t)rs*OC_*C_ + t] = f2bf(src[rs]);
}

// Pre-pass 3: Wc[18][512], Wb[36][512] -> Whb[64][512] bf16 (rows 54..63 zero)
__global__ __launch_bounds__(256) void prep_whb(const float* __restrict__ Wc,
                                                const float* __restrict__ Wb,
                                                ushortT* __restrict__ Whb) {
    int t = blockIdx.x * 256 + threadIdx.x;
    if (t >= 64*512) return;
    int o = t >> 9, oc = t & 511;
    float v = 0.f;
    if (o < 18) v = Wc[o*512 + oc];
    else if (o < 54) v = Wb[(o-18)*512 + oc];
    Whb[t] = f2bf(v);
}

// Pre-pass 4: init output with head biases, float4 stores (head is 2-way
// atomic-partial now, so bias lives here).
__global__ __launch_bounds__(256) void init_out(const float* __restrict__ bc,
                                                const float* __restrict__ bb,
                                                float* __restrict__ out) {
    int i = blockIdx.x * 256 + threadIdx.x;   // float4 index
    if (i >= OUT_TOTAL_/4) return;
    int base = i * 4;
    float4 v;
    #pragma unroll
    for (int j = 0; j < 4; ++j) {
        int idx = base + j;
        float val = (idx < OUT0_) ? bc[idx % 18] : bb[(idx - OUT0_) % 36];
        (&v.x)[j] = val;
    }
    ((float4*)out)[i] = v;
}

// ---------------------------------------------------------------------------
// Main fused kernel, v4: faithful m201 port. BM=256 x BN=256 (nh = oc half),
// BK=64, 512 threads / 8 waves (2M x 4N), wave tile 128x64, acc[2][4][4].
// LDS 128 KB (ushort idx): Abuf0 [0,16384) Abuf1 [16384,32768)
//                          Bbuf0 [32768,49152) Bbuf1 [49152,65536)
// Per K-tile: 4 phases (ph = kk*2 + mh), m201 read counts 8/4/8/4
// (A-frags read once per kk; B-frags read at mh=0, cached for mh=1).
// 1 half-tile of tile t+1 staged per phase into buf^1 (A0,A1,B0,B1 order —
// HBM-latency A halves get 3-4 phases of cover; B is L2-resident W1t).
// vmcnt(2) once per tile at phase 0 (2 loads of t+1 in flight), vmcnt(0)
// only at tile 35. Double s_barrier per phase, setprio(1) around MFMA,
// sched_barrier(0) after every inline-asm wait (rule #18).
// Head GEMM K=256 per block -> 2-way atomic partials (bias via init_out).
#define CONV_GRID 2100

#define GLD(gsrc, ldst) __builtin_amdgcn_global_load_lds( \
    (const __attribute__((address_space(1))) uint32_t*)(gsrc), \
    (__attribute__((address_space(3))) uint32_t*)(ldst), 16, 0, 0)

__global__ __launch_bounds__(512, 2) void conv_rpn(
    const ushortT* __restrict__ Xp, const ushortT* __restrict__ W1t,
    const float* __restrict__ b1,  const ushortT* __restrict__ Whb,
    float* __restrict__ out)
{
    extern __shared__ ushortT smem[];

    const int tid  = threadIdx.x;
    const int wave = tid >> 6;          // 0..7
    const int lane = tid & 63;
    const int col  = lane & 15;
    const int quad = lane >> 4;
    const int c7   = col & 7;           // read de-swizzle key (row&7 == col&7)
    const int wm   = (wave >> 2) * 128; // wave M offset (0 or 128)
    const int wn64 = (wave & 3) * 64;   // wave N offset within the 256 tile

    // Bijective XCD swizzle, 2100 blocks over 8 XCDs; consecutive seq =
    // (same mtile, both oc-halves) -> A-panel shared within one XCD's L2.
    const int bid = blockIdx.x;
    const int xcd = bid & 7, ib = bid >> 3;
    const int seq = (xcd < 4) ? (xcd*263 + ib) : (1052 + (xcd-4)*262 + ib);
    const int mtile = seq >> 1;         // 0..1049 (256 rows each)
    const int nh    = seq & 1;          // oc half: [nh*256, nh*256+256)

    // Staging: lane r8 = row-within-8-group; chunk pos lane&7 holds logical
    // chunk (lane&7)^r8 (row-XOR swizzle; linear LDS dest + pre-swizzled src).
    const int r8     = lane >> 3;
    const int lchunk = ((lane & 7) ^ r8) * 8;

    // A sources: half h (rows h*128..), load l: row h*128 + wave*16 + l*8 + r8.
    size_t pixA[2][2];
    #pragma unroll
    for (int h = 0; h < 2; ++h)
        #pragma unroll
        for (int l = 0; l < 2; ++l) {
            int m = mtile*256 + h*128 + wave*16 + l*8 + r8;
            int b = m / (H_*W_);
            int rem = m % (H_*W_);
            int hh = rem / W_;
            int ww = rem % W_;
            pixA[h][l] = (((size_t)b*HP_ + hh)*WP_ + ww)*C_ + lchunk;
        }
    // B sources: oc row nh*256 + h*128 + wave*16 + l*8 + r8.
    size_t bbase[2][2];
    #pragma unroll
    for (int h = 0; h < 2; ++h)
        #pragma unroll
        for (int l = 0; l < 2; ++l)
            bbase[h][l] = ((size_t)(nh*256 + h*128 + wave*16 + l*8 + r8))*C_
                          + lchunk;

    f32x4 acc[2][4][4] = {};   // [mh][mt][nt]

    // Stage half-tile q of a K-tile into buffer `buf` (2 GLD per wave).
    auto STAGE_HALF = [&](int q, int buf, size_t aoffn, size_t woffn) {
        if (q < 2) {
            ushortT* dst = smem + buf*16384 + (q*128 + wave*16)*64;
            GLD(Xp + pixA[q][0] + aoffn, dst);
            GLD(Xp + pixA[q][1] + aoffn, dst + 8*64);
        } else {
            int h = q - 2;
            ushortT* dst = smem + 32768 + buf*16384 + (h*128 + wave*16)*64;
            GLD(W1t + woffn + bbase[h][0], dst);
            GLD(W1t + woffn + bbase[h][1], dst + 8*64);
        }
    };

    // Prologue: stage tile 0 (rs=0, cs=0 -> aoff=woff=0) into buf0.
    STAGE_HALF(0, 0, 0, 0);
    STAGE_HALF(1, 0, 0, 0);
    STAGE_HALF(2, 0, 0, 0);
    STAGE_HALF(3, 0, 0, 0);

    #pragma unroll 1
    for (int t = 0; t < 36; ++t) {
        const int cur = t & 1;
        const ushortT* Al = smem + cur*16384;
        const ushortT* Bl = smem + 32768 + cur*16384;
        const bool pf = (t < 35);
        size_t aoffn = 0, woffn = 0;
        if (pf) {
            int tn = t + 1;
            int rsn = tn >> 2, csn = (tn & 3) << 6;
            aoffn = (size_t)((rsn/3)*WP_ + (rsn%3))*C_ + csn;
            woffn = (size_t)rsn*OC_*C_ + csn;
        }
        bf16x8 af[4], bfr[4];
        const int pc0 = (quad ^ c7) * 8;        // kk=0 chunk
        const int pc1 = ((4 + quad) ^ c7) * 8;  // kk=1 chunk

        // ---- phase 0: kk=0, mh=0 (+ fresh B frags kk=0) -------------------
        if (pf) {
            STAGE_HALF(0, cur ^ 1, aoffn, woffn);
            asm volatile("s_waitcnt vmcnt(2)" ::: "memory");
        } else {
            asm volatile("s_waitcnt vmcnt(0)" ::: "memory");
        }
        __builtin_amdgcn_sched_barrier(0);
        __builtin_amdgcn_s_barrier();
        __builtin_amdgcn_sched_barrier(0);
        #pragma unroll
        for (int mt = 0; mt < 4; ++mt)
            af[mt] = *(const bf16x8*)&Al[(wm + mt*16 + col)*64 + pc0];
        #pragma unroll
        for (int nt = 0; nt < 4; ++nt)
            bfr[nt] = *(const bf16x8*)&Bl[(wn64 + nt*16 + col)*64 + pc0];
        asm volatile("s_waitcnt lgkmcnt(0)" ::: "memory");
        __builtin_amdgcn_sched_barrier(0);
        __builtin_amdgcn_s_setprio(1);
        #pragma unroll
        for (int mt = 0; mt < 4; ++mt)
            #pragma unroll
            for (int nt = 0; nt < 4; ++nt)
                acc[0][mt][nt] = __builtin_amdgcn_mfma_f32_16x16x32_bf16(
                    af[mt], bfr[nt], acc[0][mt][nt], 0, 0, 0);
        __builtin_amdgcn_s_setprio(0);
        __builtin_amdgcn_sched_barrier(0);
        __builtin_amdgcn_s_barrier();

        // ---- phase 1: kk=0, mh=1 (B frags cached) -------------------------
        #pragma unroll
        for (int mt = 0; mt < 4; ++mt)
            af[mt] = *(const bf16x8*)&Al[(wm + 64 + mt*16 + col)*64 + pc0];
        if (pf) STAGE_HALF(1, cur ^ 1, aoffn, woffn);
        __builtin_amdgcn_s_barrier();
        asm volatile("s_waitcnt lgkmcnt(0)" ::: "memory");
        __builtin_amdgcn_sched_barrier(0);
        __builtin_amdgcn_s_setprio(1);
        #pragma unroll
        for (int mt = 0; mt < 4; ++mt)
            #pragma unroll
            for (int nt = 0; nt < 4; ++nt)
                acc[1][mt][nt] = __builtin_amdgcn_mfma_f32_16x16x32_bf16(
                    af[mt], bfr[nt], acc[1][mt][nt], 0, 0, 0);
        __builtin_amdgcn_s_setprio(0);
        __builtin_amdgcn_sched_barrier(0);
        __builtin_amdgcn_s_barrier();

        // ---- phase 2: kk=1, mh=0 (+ fresh B frags kk=1) -------------------
        #pragma unroll
        for (int mt = 0; mt < 4; ++mt)
            af[mt] = *(const bf16x8*)&Al[(wm + mt*16 + col)*64 + pc1];
        #pragma unroll
        for (int nt = 0; nt < 4; ++nt)
            bfr[nt] = *(const bf16x8*)&Bl[(wn64 + nt*16 + col)*64 + pc1];
        if (pf) STAGE_HALF(2, cur ^ 1, aoffn, woffn);
        __builtin_amdgcn_s_barrier();
        asm volatile("s_waitcnt lgkmcnt(0)" ::: "memory");
        __builtin_amdgcn_sched_barrier(0);
        __builtin_amdgcn_s_setprio(1);
        #pragma unroll
        for (int mt = 0; mt < 4; ++mt)
            #pragma unroll
            for (int nt = 0; nt < 4; ++nt)
                acc[0][mt][nt] = __builtin_amdgcn_mfma_f32_16x16x32_bf16(
                    af[mt], bfr[nt], acc[0][mt][nt], 0, 0, 0);
        __builtin_amdgcn_s_setprio(0);
        __builtin_amdgcn_sched_barrier(0);
        __builtin_amdgcn_s_barrier();

        // ---- phase 3: kk=1, mh=1 ------------------------------------------
        #pragma unroll
        for (int mt = 0; mt < 4; ++mt)
            af[mt] = *(const bf16x8*)&Al[(wm + 64 + mt*16 + col)*64 + pc1];
        if (pf) STAGE_HALF(3, cur ^ 1, aoffn, woffn);
        __builtin_amdgcn_s_barrier();
        asm volatile("s_waitcnt lgkmcnt(0)" ::: "memory");
        __builtin_amdgcn_sched_barrier(0);
        __builtin_amdgcn_s_setprio(1);
        #pragma unroll
        for (int mt = 0; mt < 4; ++mt)
            #pragma unroll
            for (int nt = 0; nt < 4; ++nt)
                acc[1][mt][nt] = __builtin_amdgcn_mfma_f32_16x16x32_bf16(
                    af[mt], bfr[nt], acc[1][mt][nt], 0, 0, 0);
        __builtin_amdgcn_s_setprio(0);
        __builtin_amdgcn_sched_barrier(0);
        __builtin_amdgcn_s_barrier();
    }

    // ---- Epilogue: +b1, ReLU, feat -> Fsm[256][256] bf16 (reuses all LDS).
    // Swizzle: chunk (colc>>3, 0..31) XOR (row&7), involution on read.
    // Safe: tile-35 closing barrier has all ds_reads drained & GLDs landed.
    ushortT* Fsm = smem;
    float b1v[4];
    #pragma unroll
    for (int mh = 0; mh < 2; ++mh) {
        if (mh == 0) {
            #pragma unroll
            for (int nt = 0; nt < 4; ++nt)
                b1v[nt] = b1[nh*256 + wn64 + nt*16 + col];
        }
        #pragma unroll
        for (int mt = 0; mt < 4; ++mt)
            #pragma unroll
            for (int nt = 0; nt < 4; ++nt) {
                const float bv = b1v[nt];
                #pragma unroll
                for (int rg = 0; rg < 4; ++rg) {
                    int row  = wm + mh*64 + mt*16 + quad*4 + rg;
                    int colc = wn64 + nt*16 + col;
                    float v = fmaxf(acc[mh][mt][nt][rg] + bv, 0.f);
                    int pos = (((colc >> 3) ^ (row & 7)) << 3) | (colc & 7);
                    Fsm[row*256 + pos] = f2bf(v);
                }
            }
    }
    __syncthreads();

    // ---- Head GEMM: M=256 px, N=64 (54 used), K=256 (this block's oc half).
    f32x4 hacc[2][4] = {};
    const int h7 = col & 7;    // hrow&7 == col&7
    #pragma unroll
    for (int ks = 0; ks < 8; ++ks) {
        bf16x8 ah[2];
        #pragma unroll
        for (int mt = 0; mt < 2; ++mt) {
            int hrow = wave*32 + mt*16 + col;
            ah[mt] = *(const bf16x8*)&Fsm[hrow*256
                        + (((ks*4 + quad) ^ h7) << 3)];
        }
        #pragma unroll
        for (int nt = 0; nt < 4; ++nt) {
            bf16x8 bh = *(const bf16x8*)&Whb[(nt*16 + col)*512
                        + nh*256 + ks*32 + quad*8];
            #pragma unroll
            for (int mt = 0; mt < 2; ++mt)
                hacc[mt][nt] = __builtin_amdgcn_mfma_f32_16x16x32_bf16(
                    ah[mt], bh, hacc[mt][nt], 0, 0, 0);
        }
    }

    // ---- 2-way atomic partial accumulation (bias pre-loaded by init_out).
    #pragma unroll
    for (int mt = 0; mt < 2; ++mt) {
        int mbase = mtile*256 + wave*32 + mt*16 + quad*4;
        #pragma unroll
        for (int nt = 0; nt < 4; ++nt) {
            int o = nt*16 + col;
            #pragma unroll
            for (int rg = 0; rg < 4; ++rg) {
                float v = hacc[mt][nt][rg];
                size_t p = (size_t)(mbase + rg);
                if (o < 18)      atomicAdd(out + p*18 + o, v);
                else if (o < 54) atomicAdd(out + OUT0_ + p*36 + (o - 18), v);
            }
        }
    }
}

// ---------------------------------------------------------------------------
extern "C" void kernel_launch(void* const* d_in, const int* in_sizes, int n_in,
                              void* d_out, int out_size, void* d_ws, size_t ws_size,
                              hipStream_t stream) {
    const float* X  = (const float*)d_in[0];
    const float* W1 = (const float*)d_in[1];
    const float* b1 = (const float*)d_in[2];
    const float* Wc = (const float*)d_in[3];
    const float* bc = (const float*)d_in[4];
    const float* Wb = (const float*)d_in[5];
    const float* bb = (const float*)d_in[6];
    float* out = (float*)d_out;

    ushortT* Xp  = (ushortT*)d_ws;
    ushortT* W1t = (ushortT*)((char*)d_ws + W1T_OFF);
    ushortT* Whb = (ushortT*)((char*)d_ws + WHB_OFF);

    static bool attr_set = false;
    if (!attr_set) {
        hipFuncSetAttribute((const void*)conv_rpn,
                            hipFuncAttributeMaxDynamicSharedMemorySize, 131072);
        attr_set = true;
    }

    zero_halo<<<(4*1076*32 + 255)/256, 256, 0, stream>>>(Xp);
    pad_transpose<<<B_*H_*6, 256, 0, stream>>>(X, Xp);
    prep_w1<<<(OC_*C_ + 255)/256, 256, 0, stream>>>(W1, W1t);
    prep_whb<<<(64*512 + 255)/256, 256, 0, stream>>>(Wc, Wb, Whb);
    init_out<<<(OUT_TOTAL_/4 + 255)/256, 256, 0, stream>>>(bc, bb, out);
    conv_rpn<<<CONV_GRID, 512, 131072, stream>>>(Xp, W1t, b1, Whb, out);
}